// Round 3
// baseline (605677.441 us; speedup 1.0000x reference)
//
#include <hip/hip_runtime.h>
#include <hip/hip_fp16.h>
#include <cstdint>
#include <cstddef>

// Problem constants
#define B_   64
#define S_   512
#define F_   512
#define H_   1024
#define KTOT 1536          // H + F augmented K
#define EPS_ 1e-3f
#define NBLK 256

typedef _Float16 f16x8 __attribute__((ext_vector_type(8)));
typedef float    f32x4 __attribute__((ext_vector_type(4)));

// workspace layout (bytes)
#define WS_CNT_OFF   0            // 8 u32 xcd rank counters
#define WS_FLAG_OFF  128          // [8 xcd][32 rank][4 wave] u32 = 4 KB
#define WS_HBUF_OFF  8192         // [3][64][1024] fp16 = 384 KB
#define WS_WT_OFF    (512*1024)   // [3*1024][1536] fp16 = 9 MB
#define LDS_BYTES    (96*1024)    // forces 1 block/CU (160 KB LDS pool)

#define MFMA16(A,Bf,C) __builtin_amdgcn_mfma_f32_16x16x32_f16(A, Bf, C, 0, 0, 0)

// ---------------- weight prep: fp16, transposed, [3*H][KTOT] ----------------
__global__ void prep_weights(const float* __restrict__ Wr, const float* __restrict__ Wc,
                             const float* __restrict__ Wo, const float* __restrict__ Ur,
                             const float* __restrict__ Uc, const float* __restrict__ Uo,
                             _Float16* __restrict__ Wt) {
    int b  = blockIdx.x;            // 0..191
    int g  = b >> 6;                // gate 0..2
    int j0 = (b & 63) << 4;         // 16 columns per block
    const float* W = (g == 0) ? Wr : (g == 1) ? Wc : Wo;
    const float* U = (g == 0) ? Ur : (g == 1) ? Uc : Uo;
    int jj = threadIdx.x & 15;
    int kk = threadIdx.x >> 4;      // 0..15
    for (int k0 = 0; k0 < KTOT; k0 += 16) {
        int k = k0 + kk;
        float v = (k < H_) ? W[(size_t)k * H_ + j0 + jj]
                           : U[(size_t)(k - H_) * H_ + j0 + jj];
        Wt[(size_t)(g * H_ + j0 + jj) * KTOT + k] = (_Float16)v;
    }
}

// ---------------- persistent XCD-local recurrence kernel ----------------
// 256 blocks, 1/CU (96KB LDS). XCD g owns batch rows [8g, 8g+8).
// Block (g, rank): 8 rows x 32 h-cols x 3 gates; 4 waves K-split (384 each).
// All h exchange + flags stay in the XCD's private L2 (sc0-only coherence:
// L1 is write-through, sc0 loads bypass L1, L2 is shared by the 32 CUs).
__launch_bounds__(256, 1)
__global__ void plstm_xcd(const float* __restrict__ x,
                          const float* __restrict__ ts,
                          const float* __restrict__ br,
                          const float* __restrict__ bc,
                          const float* __restrict__ bo,
                          const _Float16* __restrict__ Wt,
                          _Float16* __restrict__ hbuf,    // [3][64][1024] fp16
                          unsigned* __restrict__ flags,   // [8][32][4]
                          unsigned* __restrict__ xcdcnt,  // [8]
                          float* __restrict__ out) {
    extern __shared__ char lds[];
    float* red  = (float*)lds;              // [4 waves][3 gates][8*32] = 12 KB
    int*  sslot = (int*)(lds + 12288);

    const int tid = threadIdx.x;
    if (tid == 0) {
        unsigned xcc;
        asm volatile("s_getreg_b32 %0, hwreg(HW_REG_XCC_ID)" : "=s"(xcc));
        xcc &= 7u;
        unsigned r = __hip_atomic_fetch_add(&xcdcnt[xcc], 1u,
                                            __ATOMIC_RELAXED, __HIP_MEMORY_SCOPE_AGENT);
        sslot[0] = (int)(xcc * 32u + (r & 31u));
    }
    __syncthreads();
    const int slot = sslot[0];
    const int g    = slot >> 5;          // XCD id = batch-row group
    const int rank = slot & 31;          // 0..31 within XCD
    const int c0   = rank << 5;          // 32 h-cols per block

    const int lane = tid & 63;
    const int w    = tid >> 6;           // wave: K range [256w,256w+256)+[1024+128w,+128)
    const int kblk = lane >> 4;          // 0..3
    const int jcol = lane & 15;          // B-fragment column within 16-col tile
    const int arow = g * 8 + (lane & 7); // A rows 8-15 duplicate 0-7 (M=8 used of 16)

    const int erow = tid >> 5;           // elementwise: 8 rows x 32 cols = 256 threads
    const int ecol = tid & 31;
    const int gb   = g * 8 + erow;
    const int gh   = c0 + ecol;
    const float biasr = br[gh], biasc = bc[gh], biaso = bo[gh];
    float cst = 0.f, kst = 0.f, hval = 0.f;

    // ---- weights into registers: 3 gates x 2 col-tiles x 12 subk = 288 VGPR ----
    f16x8 bf[3][2][12];
    #pragma unroll
    for (int g3 = 0; g3 < 3; ++g3)
        #pragma unroll
        for (int ct = 0; ct < 2; ++ct)
            #pragma unroll
            for (int sub = 0; sub < 12; ++sub) {
                const int kb = (sub < 8) ? (w * 256 + sub * 32)
                                         : (H_ + w * 128 + (sub - 8) * 32);
                bf[g3][ct][sub] = *(const f16x8*)(Wt
                    + (size_t)(g3 * H_ + c0 + ct * 16 + jcol) * KTOT + kb + kblk * 8);
            }

    unsigned* const myflag = flags + g * 128 + rank * 4 + w;        // producer flag
    const unsigned* const myfl = flags + g * 128 + w * 32 + (lane & 31); // 32 producer-wave flags

    // x prefetch double-buffer (f32 regs, cvt to fp16 at use)
    f32x4 xA[8], xB[8];
    #pragma unroll
    for (int i = 0; i < 4; ++i) {
        const float* xp = x + (size_t)arow * S_ * F_ + w * 128 + i * 32 + kblk * 8;
        xA[2 * i]     = *(const f32x4*)xp;
        xA[2 * i + 1] = *(const f32x4*)(xp + 4);
    }

    auto step = [&](int t, f32x4* xc, f32x4* xn) {
        // ---- poll this wave's 32 producer-wave flags (XCD-local L2) ----
        if (t > 0) {
            for (unsigned it = 0; it < (1u << 14); ++it) {
                unsigned v;
                asm volatile("global_load_dword %0, %1, off sc0\n\t"
                             "s_waitcnt vmcnt(0)"
                             : "=v"(v) : "v"(myfl) : "memory");
                if (__all((int)(v >= (unsigned)t))) break;
            }
        }
        const float tv = ts[(size_t)gb * S_ + t];   // issued early, used late

        // ---- h A-fragments from XCD-local L2 ----
        const _Float16* hb = hbuf + (size_t)(t % 3) * B_ * H_;
        f16x8 hfr[8];
        #pragma unroll
        for (int sub = 0; sub < 8; ++sub) {
            const _Float16* hp = hb + (size_t)arow * H_ + w * 256 + sub * 32 + kblk * 8;
            asm volatile("global_load_dwordx4 %0, %1, off sc0"
                         : "=v"(hfr[sub]) : "v"(hp));
        }
        asm volatile("s_waitcnt vmcnt(0)" ::: "memory");
        __builtin_amdgcn_sched_barrier(0);

        // ---- MFMA: 3 gates x 2 col-tiles x (8 h-subk + 4 x-subk) = 72 ----
        f32x4 a00 = {0,0,0,0}, a01 = {0,0,0,0}, a10 = {0,0,0,0},
              a11 = {0,0,0,0}, a20 = {0,0,0,0}, a21 = {0,0,0,0};
        #pragma unroll
        for (int sub = 0; sub < 8; ++sub) {
            a00 = MFMA16(hfr[sub], bf[0][0][sub], a00);
            a01 = MFMA16(hfr[sub], bf[0][1][sub], a01);
            a10 = MFMA16(hfr[sub], bf[1][0][sub], a10);
            a11 = MFMA16(hfr[sub], bf[1][1][sub], a11);
            a20 = MFMA16(hfr[sub], bf[2][0][sub], a20);
            a21 = MFMA16(hfr[sub], bf[2][1][sub], a21);
        }
        #pragma unroll
        for (int i = 0; i < 4; ++i) {
            f16x8 a;
            #pragma unroll
            for (int r = 0; r < 4; ++r) {
                a[r]     = (_Float16)xc[2 * i][r];
                a[4 + r] = (_Float16)xc[2 * i + 1][r];
            }
            a00 = MFMA16(a, bf[0][0][8 + i], a00);
            a01 = MFMA16(a, bf[0][1][8 + i], a01);
            a10 = MFMA16(a, bf[1][0][8 + i], a10);
            a11 = MFMA16(a, bf[1][1][8 + i], a11);
            a20 = MFMA16(a, bf[2][0][8 + i], a20);
            a21 = MFMA16(a, bf[2][1][8 + i], a21);
        }

        // ---- cross-wave reduce (C rows 0-7 live in lanes 0-31) ----
        if (lane < 32) {
            float* rw = red + w * 768;
            const int crow = (lane >> 4) * 4;
            const int ccol = lane & 15;
            #pragma unroll
            for (int i = 0; i < 4; ++i) {
                const int rr = (crow + i) * 32 + ccol;
                rw[rr]            = a00[i];
                rw[rr + 16]       = a01[i];
                rw[256 + rr]      = a10[i];
                rw[256 + rr + 16] = a11[i];
                rw[512 + rr]      = a20[i];
                rw[512 + rr + 16] = a21[i];
            }
        }
        __syncthreads();
        float pr = biasr, pc = biasc, po = biaso;
        #pragma unroll
        for (int ww = 0; ww < 4; ++ww) {
            pr += red[ww * 768 + tid];
            pc += red[ww * 768 + 256 + tid];
            po += red[ww * 768 + 512 + tid];
        }

        // ---- elementwise pLSTM update (f32) ----
        const float r = 1.f / (1.f + __expf(-pr));
        kst = r * tv + (1.f - r) * kst;
        const float e2 = __expf(2.f * pc);
        const float ctil = (e2 - 1.f) / (e2 + 1.f);
        const float d = tv - kst;
        const float f = __fsqrt_rn((d + EPS_) / (d + 1.f));  // ((d+1)/(d+eps))^-0.5
        cst = f * cst + (1.f - f) * ctil;
        const float o = 1.f / (1.f + __expf(-po));
        const float e2c = __expf(2.f * cst);
        hval = o * ((e2c - 1.f) / (e2c + 1.f));

        if (t + 1 < S_) {
            // publish own h element (2B, sc0 -> XCD L2), drain, set wave flag
            union { _Float16 hf; unsigned short us; } cv; cv.hf = (_Float16)hval;
            unsigned short* hp = (unsigned short*)(hbuf
                + (size_t)((t + 1) % 3) * B_ * H_ + (size_t)gb * H_ + gh);
            unsigned uval = cv.us;
            asm volatile("global_store_short %0, %1, off sc0"
                         :: "v"(hp), "v"(uval) : "memory");
            asm volatile("s_waitcnt vmcnt(0)" ::: "memory");
            if (lane == 0) {
                unsigned fv = (unsigned)(t + 1);
                asm volatile("global_store_dword %0, %1, off sc0"
                             :: "v"(myflag), "v"(fv) : "memory");
            }
            // x prefetch for t+1 (after the flag so vmcnt(0) above stays cheap)
            #pragma unroll
            for (int i = 0; i < 4; ++i) {
                const float* xp = x + ((size_t)arow * S_ + (t + 1)) * F_
                                    + w * 128 + i * 32 + kblk * 8;
                xn[2 * i]     = *(const f32x4*)xp;
                xn[2 * i + 1] = *(const f32x4*)(xp + 4);
            }
        }
        out[((size_t)gb * S_ + t) * H_ + gh] = hval;   // fire-and-forget
    };

    for (int t = 0; t < S_; t += 2) {
        step(t,     xA, xB);
        step(t + 1, xB, xA);
    }

    // final states
    const size_t BSH = (size_t)B_ * S_ * H_;
    out[BSH +                       (size_t)gb * H_ + gh] = hval;  // h_T
    out[BSH + (size_t)B_ * H_ +     (size_t)gb * H_ + gh] = cst;   // c_T
    out[BSH + 2 * (size_t)B_ * H_ + (size_t)gb * H_ + gh] = kst;   // k_T
}

extern "C" void kernel_launch(void* const* d_in, const int* in_sizes, int n_in,
                              void* d_out, int out_size, void* d_ws, size_t ws_size,
                              hipStream_t stream) {
    (void)in_sizes; (void)n_in; (void)out_size; (void)ws_size;
    const float* x  = (const float*)d_in[0];
    const float* ts = (const float*)d_in[1];
    const float* Ur = (const float*)d_in[2];
    const float* Wr = (const float*)d_in[3];
    const float* br = (const float*)d_in[4];
    const float* Uc = (const float*)d_in[5];
    const float* Wc = (const float*)d_in[6];
    const float* bc = (const float*)d_in[7];
    const float* Uo = (const float*)d_in[8];
    const float* Wo = (const float*)d_in[9];
    const float* bo = (const float*)d_in[10];
    float* out = (float*)d_out;

    char* ws = (char*)d_ws;
    unsigned*  xcdcnt = (unsigned*)(ws + WS_CNT_OFF);
    unsigned*  flags  = (unsigned*)(ws + WS_FLAG_OFF);
    _Float16*  hbuf   = (_Float16*)(ws + WS_HBUF_OFF);
    _Float16*  Wt     = (_Float16*)(ws + WS_WT_OFF);

    // zero rank counters + flags + h buffer 0 (h_0 = 0); re-done every launch
    hipMemsetAsync(ws, 0, WS_HBUF_OFF + B_ * H_ * 2, stream);

    prep_weights<<<192, 256, 0, stream>>>(Wr, Wc, Wo, Ur, Uc, Uo, Wt);

    hipFuncSetAttribute((const void*)plstm_xcd,
                        hipFuncAttributeMaxDynamicSharedMemorySize, LDS_BYTES);
    plstm_xcd<<<NBLK, 256, LDS_BYTES, stream>>>(x, ts, br, bc, bo, Wt,
                                                hbuf, flags, xcdcnt, out);
}

// Round 4
// 2610.690 us; speedup vs baseline: 231.9990x; 231.9990x over previous
//
#include <hip/hip_runtime.h>
#include <hip/hip_fp16.h>
#include <cstdint>
#include <cstddef>

// Problem constants
#define B_   64
#define S_   512
#define F_   512
#define H_   1024
#define KTOT 1536
#define EPS_ 1e-3f
#define NBLK 256
#define NTHR 512

typedef _Float16 f16x8 __attribute__((ext_vector_type(8)));
typedef float    f32x4 __attribute__((ext_vector_type(4)));
typedef unsigned u32x4 __attribute__((ext_vector_type(4)));

// workspace layout (bytes)
#define WS_HBUF_OFF 0                 // tagged h: u32[3][64][1024] = 768 KB
#define WS_WT_OFF   (1024*1024)       // fp16 [3*1024][1536] = 9 MB
#define LDS_XW      (96*1024)         // x-part weights in LDS
#define LDS_BYTES   (LDS_XW + 24*1024)

#define MFMA16(A,Bf,C) __builtin_amdgcn_mfma_f32_16x16x32_f16(A, Bf, C, 0, 0, 0)

// ---------------- weight prep: fp16, transposed, [3*H][KTOT] ----------------
// Wt[(g*H + j)][k] = (k < H) ? W_g[k][j] : U_g[k-H][j]
__global__ void prep_weights(const float* __restrict__ Wr, const float* __restrict__ Wc,
                             const float* __restrict__ Wo, const float* __restrict__ Ur,
                             const float* __restrict__ Uc, const float* __restrict__ Uo,
                             _Float16* __restrict__ Wt) {
    int b  = blockIdx.x;            // 0..191
    int g  = b >> 6;                // gate 0..2
    int j0 = (b & 63) << 4;         // 16 columns per block
    const float* W = (g == 0) ? Wr : (g == 1) ? Wc : Wo;
    const float* U = (g == 0) ? Ur : (g == 1) ? Uc : Uo;
    int jj = threadIdx.x & 15;
    int kk = threadIdx.x >> 4;      // 0..15
    for (int k0 = 0; k0 < KTOT; k0 += 16) {
        int k = k0 + kk;
        float v = (k < H_) ? W[(size_t)k * H_ + j0 + jj]
                           : U[(size_t)(k - H_) * H_ + j0 + jj];
        Wt[(size_t)(g * H_ + j0 + jj) * KTOT + k] = (_Float16)v;
    }
}

// ---------------- persistent tagged-h recurrence kernel ----------------
// 256 blocks x 512 threads (8 waves, 2/SIMD). Logical partition only:
// group = bid>>5 (8 batch rows), cg = bid&31 (32 h-cols). Wave w K-split:
// h-k [128w,128w+128), x-k [64w,64w+64). h exchanged as {tag,fp16} u32 words
// (tear-free: tag+data share one 4B word) -> ONE LLC round trip per step.
__global__ __launch_bounds__(NTHR, 2)
void plstm_tag(const float* __restrict__ x,
               const float* __restrict__ ts,
               const float* __restrict__ br,
               const float* __restrict__ bc,
               const float* __restrict__ bo,
               const _Float16* __restrict__ Wt,
               unsigned* __restrict__ hbuf,     // [3][64][1024] u32 tagged
               float* __restrict__ out) {
    extern __shared__ char lds[];
    float* red = (float*)(lds + LDS_XW);   // [8 waves][3 gates][8*32] = 24 KB

    const int tid = threadIdx.x;
    const int bid = blockIdx.x;
    const int grp = bid >> 5;            // batch-row group 0..7
    const int cg  = bid & 31;            // h-col group 0..31
    const int r0  = grp << 3;            // 8 rows
    const int c0  = cg << 5;             // 32 cols

    const int lane = tid & 63;
    const int w    = tid >> 6;           // wave 0..7
    const int arow = r0 + (lane & 7);    // A rows 8-15 duplicate 0-7 (M=8 of 16)
    const int kblk = lane >> 4;          // 0..3
    const int jcol = lane & 15;          // B-fragment column within 16-col tile

    // ---- stage x-part weights into LDS: row R=(g3*2+ct)*16+jcol, 512 k, swizzled ----
    for (int m = tid; m < 96 * 64; m += NTHR) {
        const int R  = m >> 6;           // 0..95
        const int kc = m & 63;           // 8-elem chunk along x-k
        const int g3 = R >> 5;
        const int rem = R & 31;          // ct*16 + jcol
        f16x8 v = *(const f16x8*)(Wt + (size_t)(g3 * H_ + c0 + rem) * KTOT + H_ + kc * 8);
        const int dst = (R * 1024 + kc * 16) ^ ((R & 7) << 4);
        *(f16x8*)(lds + dst) = v;
    }

    // ---- h-part weights to registers: 3 gates x 2 col-tiles x 4 subk = 96 VGPR ----
    f16x8 bf[3][2][4];
    #pragma unroll
    for (int g3 = 0; g3 < 3; ++g3)
        #pragma unroll
        for (int ct = 0; ct < 2; ++ct)
            #pragma unroll
            for (int sub = 0; sub < 4; ++sub)
                bf[g3][ct][sub] = *(const f16x8*)(Wt
                    + (size_t)(g3 * H_ + c0 + ct * 16 + jcol) * KTOT
                    + w * 128 + sub * 32 + kblk * 8);
    __syncthreads();

    const bool owner = (tid < 256);      // elementwise: 8 rows x 32 cols
    const int erow = tid >> 5;
    const int ecol = tid & 31;
    const int gb   = r0 + erow;
    const int gh   = c0 + ecol;
    float biasr = 0.f, biasc = 0.f, biaso = 0.f;
    if (owner) { biasr = br[gh]; biasc = bc[gh]; biaso = bo[gh]; }
    float cst = 0.f, kst = 0.f, hval = 0.f;

    for (int t = 0; t < S_; ++t) {
        // ---- issue x loads (cached, pinned order via asm) ----
        const float* xrow = x + ((size_t)arow * S_ + t) * F_ + w * 64 + kblk * 8;
        f32x4 xq0, xq1, xq2, xq3;
        asm volatile("global_load_dwordx4 %0, %1, off" : "=v"(xq0) : "v"(xrow));
        asm volatile("global_load_dwordx4 %0, %1, off" : "=v"(xq1) : "v"(xrow + 4));
        asm volatile("global_load_dwordx4 %0, %1, off" : "=v"(xq2) : "v"(xrow + 32));
        asm volatile("global_load_dwordx4 %0, %1, off" : "=v"(xq3) : "v"(xrow + 36));

        // ---- pre-issue tag-load iteration 0 ----
        const unsigned* hb = hbuf + (size_t)(t % 3) * B_ * H_
                                  + (size_t)arow * H_ + w * 128 + kblk * 8;
        u32x4 q[8];
        #pragma unroll
        for (int s = 0; s < 4; ++s) {
            asm volatile("global_load_dwordx4 %0, %1, off sc0 sc1"
                         : "=v"(q[2 * s]) : "v"(hb + s * 32));
            asm volatile("global_load_dwordx4 %0, %1, off sc0 sc1"
                         : "=v"(q[2 * s + 1]) : "v"(hb + s * 32 + 4));
        }
        asm volatile("s_waitcnt vmcnt(8)" ::: "memory");   // x quads ready
        __builtin_amdgcn_sched_barrier(0);

        float tv = 0.f;
        if (owner) tv = ts[(size_t)gb * S_ + t];

        // ---- x-part MFMAs during the tag round trip ----
        f16x8 xf[2];
        #pragma unroll
        for (int r = 0; r < 4; ++r) { xf[0][r] = (_Float16)xq0[r]; xf[0][4 + r] = (_Float16)xq1[r]; }
        #pragma unroll
        for (int r = 0; r < 4; ++r) { xf[1][r] = (_Float16)xq2[r]; xf[1][4 + r] = (_Float16)xq3[r]; }

        f32x4 acc[3][2] = {};
        #pragma unroll
        for (int s = 0; s < 2; ++s)
            #pragma unroll
            for (int g3 = 0; g3 < 3; ++g3) {
                const int koff = (w * 64 + s * 32 + kblk * 8) * 2;
                const int sw   = (jcol & 7) << 4;
                f16x8 w0 = *(const f16x8*)(lds + ((((g3 * 2 + 0) * 16 + jcol) * 1024 + koff) ^ sw));
                f16x8 w1 = *(const f16x8*)(lds + ((((g3 * 2 + 1) * 16 + jcol) * 1024 + koff) ^ sw));
                acc[g3][0] = MFMA16(xf[s], w0, acc[g3][0]);
                acc[g3][1] = MFMA16(xf[s], w1, acc[g3][1]);
            }

        // ---- poll: all 64 h elems must carry tag == t ----
        const unsigned tt = ((unsigned)t << 16) | (unsigned)t;
        for (unsigned it = 0; it < (1u << 13); ++it) {
            asm volatile("s_waitcnt vmcnt(0)" ::: "memory");
            __builtin_amdgcn_sched_barrier(0);
            unsigned bad = 0;
            #pragma unroll
            for (int i = 0; i < 8; ++i) {
                unsigned t0 = __builtin_amdgcn_perm(q[i][1], q[i][0], 0x07060302u);
                unsigned t1 = __builtin_amdgcn_perm(q[i][3], q[i][2], 0x07060302u);
                bad |= (t0 ^ tt) | (t1 ^ tt);
            }
            if (__all(bad == 0)) break;
            #pragma unroll
            for (int s = 0; s < 4; ++s) {
                asm volatile("global_load_dwordx4 %0, %1, off sc0 sc1"
                             : "=v"(q[2 * s]) : "v"(hb + s * 32));
                asm volatile("global_load_dwordx4 %0, %1, off sc0 sc1"
                             : "=v"(q[2 * s + 1]) : "v"(hb + s * 32 + 4));
            }
        }

        // ---- unpack h fragments (strip tags) ----
        f16x8 hfr[4];
        #pragma unroll
        for (int s = 0; s < 4; ++s) {
            union { u32x4 u; f16x8 f; } cv;
            cv.u[0] = __builtin_amdgcn_perm(q[2 * s][1],     q[2 * s][0],     0x05040100u);
            cv.u[1] = __builtin_amdgcn_perm(q[2 * s][3],     q[2 * s][2],     0x05040100u);
            cv.u[2] = __builtin_amdgcn_perm(q[2 * s + 1][1], q[2 * s + 1][0], 0x05040100u);
            cv.u[3] = __builtin_amdgcn_perm(q[2 * s + 1][3], q[2 * s + 1][2], 0x05040100u);
            hfr[s] = cv.f;
        }

        // ---- h-part MFMAs ----
        #pragma unroll
        for (int s = 0; s < 4; ++s)
            #pragma unroll
            for (int g3 = 0; g3 < 3; ++g3) {
                acc[g3][0] = MFMA16(hfr[s], bf[g3][0][s], acc[g3][0]);
                acc[g3][1] = MFMA16(hfr[s], bf[g3][1][s], acc[g3][1]);
            }

        // ---- cross-wave reduce (C rows 0-7 in lanes 0-31) ----
        if (lane < 32) {
            float* rw = red + w * 768;
            const int crow = (lane >> 4) << 2;
            const int ccol = lane & 15;
            #pragma unroll
            for (int i = 0; i < 4; ++i) {
                const int rr = (crow + i) * 32 + ccol;
                rw[rr]             = acc[0][0][i];  rw[rr + 16]       = acc[0][1][i];
                rw[256 + rr]       = acc[1][0][i];  rw[256 + rr + 16] = acc[1][1][i];
                rw[512 + rr]       = acc[2][0][i];  rw[512 + rr + 16] = acc[2][1][i];
            }
        }
        __syncthreads();   // single barrier per step

        if (owner) {
            float pr = biasr, pc = biasc, po = biaso;
            #pragma unroll
            for (int ww = 0; ww < 8; ++ww) {
                pr += red[ww * 768 + tid];
                pc += red[ww * 768 + 256 + tid];
                po += red[ww * 768 + 512 + tid];
            }
            // elementwise pLSTM update (f32)
            const float r = 1.f / (1.f + __expf(-pr));
            kst = r * tv + (1.f - r) * kst;
            const float e2 = __expf(2.f * pc);
            const float ctil = (e2 - 1.f) / (e2 + 1.f);
            const float d = tv - kst;
            const float f = __fsqrt_rn((d + EPS_) / (d + 1.f));  // ((d+1)/(d+eps))^-0.5
            cst = f * cst + (1.f - f) * ctil;
            const float o = 1.f / (1.f + __expf(-po));
            const float e2c = __expf(2.f * cst);
            hval = o * ((e2c - 1.f) / (e2c + 1.f));

            if (t + 1 < S_) {
                union { _Float16 hf; unsigned short us; } cv; cv.hf = (_Float16)hval;
                const unsigned word = ((unsigned)(t + 1) << 16) | (unsigned)cv.us;
                unsigned* hp = hbuf + (size_t)((t + 1) % 3) * B_ * H_ + (size_t)gb * H_ + gh;
                asm volatile("global_store_dword %0, %1, off sc0 sc1"
                             :: "v"(hp), "v"(word) : "memory");
            }
            out[((size_t)gb * S_ + t) * H_ + gh] = hval;   // fire-and-forget
        }
    }

    if (owner) {
        const size_t BSH = (size_t)B_ * S_ * H_;
        out[BSH +                       (size_t)gb * H_ + gh] = hval;  // h_T
        out[BSH + (size_t)B_ * H_ +     (size_t)gb * H_ + gh] = cst;   // c_T
        out[BSH + 2 * (size_t)B_ * H_ + (size_t)gb * H_ + gh] = kst;   // k_T
    }
}

extern "C" void kernel_launch(void* const* d_in, const int* in_sizes, int n_in,
                              void* d_out, int out_size, void* d_ws, size_t ws_size,
                              hipStream_t stream) {
    (void)in_sizes; (void)n_in; (void)out_size; (void)ws_size;
    const float* x  = (const float*)d_in[0];
    const float* ts = (const float*)d_in[1];
    const float* Ur = (const float*)d_in[2];
    const float* Wr = (const float*)d_in[3];
    const float* br = (const float*)d_in[4];
    const float* Uc = (const float*)d_in[5];
    const float* Wc = (const float*)d_in[6];
    const float* bc = (const float*)d_in[7];
    const float* Uo = (const float*)d_in[8];
    const float* Wo = (const float*)d_in[9];
    const float* bo = (const float*)d_in[10];
    float* out = (float*)d_out;

    char* ws = (char*)d_ws;
    unsigned*  hbuf = (unsigned*)(ws + WS_HBUF_OFF);
    _Float16*  Wt   = (_Float16*)(ws + WS_WT_OFF);

    // zero ALL 3 tagged-h slots every launch: kills stale tags from the
    // previous graph replay (exact-match tags would false-positive otherwise).
    // Slot 0 zeroed = {tag 0, h=0} = valid h_0 for step 0.
    hipMemsetAsync(hbuf, 0, 3 * B_ * H_ * 4, stream);

    prep_weights<<<192, 256, 0, stream>>>(Wr, Wc, Wo, Ur, Uc, Uo, Wt);

    hipFuncSetAttribute((const void*)plstm_tag,
                        hipFuncAttributeMaxDynamicSharedMemorySize, LDS_BYTES);
    plstm_tag<<<NBLK, NTHR, LDS_BYTES, stream>>>(x, ts, br, bc, bo, Wt, hbuf, out);
}